// Round 10
// baseline (284.243 us; speedup 1.0000x reference)
//
#include <hip/hip_runtime.h>
#include <hip/hip_bf16.h>

typedef unsigned short u16;
typedef short bf16x8 __attribute__((ext_vector_type(8)));
typedef float f32x4 __attribute__((ext_vector_type(4)));

#define NXC 768
#define NHEAD 12
#define SEQ 2048
#define BSZ 2
#define HD 64
#define NCHUNK 40   // sum over 16 q-tiles of ceil(128*(bx+1)/512)
#define LOG2E 1.4426950408889634f

__device__ inline u16 f2bf(float f) {
    unsigned int u = __float_as_uint(f);
    unsigned int r = u + 0x7fffu + ((u >> 16) & 1u);
    return (u16)(r >> 16);
}
__device__ inline unsigned pk2(float lo, float hi) {
    return (unsigned)f2bf(lo) | ((unsigned)f2bf(hi) << 16);
}
__device__ inline float ex2(float x) { return __builtin_amdgcn_exp2f(x); }

// ---------------- prep kernels ----------------
__global__ void cast4_kernel(const float* __restrict__ in, u16* __restrict__ out, int n4) {
    int i = blockIdx.x * 256 + threadIdx.x;
    if (i >= n4) return;
    float4 v = ((const float4*)in)[i];
    ushort4 o;
    o.x = f2bf(v.x); o.y = f2bf(v.y); o.z = f2bf(v.z); o.w = f2bf(v.w);
    ((ushort4*)out)[i] = o;
}

// out[C][R] = in[R][C], fp32 -> bf16
__global__ void transpose_cast_kernel(const float* __restrict__ in, u16* __restrict__ out,
                                      int R, int C) {
    __shared__ float tile[32][33];
    int cb = blockIdx.x * 32, rb = blockIdx.y * 32;
    int tx = threadIdx.x, ty = threadIdx.y;   // block (32,8)
    #pragma unroll
    for (int i = 0; i < 32; i += 8)
        tile[ty + i][tx] = in[(size_t)(rb + ty + i) * C + cb + tx];
    __syncthreads();
    #pragma unroll
    for (int i = 0; i < 32; i += 8)
        out[(size_t)(cb + ty + i) * R + rb + tx] = f2bf(tile[tx][ty + i]);
}

// per-head transpose: Vb head-chunk [ss][dd] -> Vtg [dd][ss] (both bf16)
__global__ __launch_bounds__(256) void vt_kernel(const u16* __restrict__ Vb,
                                                 u16* __restrict__ Vtg) {
    __shared__ u16 tile[64][68];
    int y = blockIdx.y;                        // b*NHEAD+h
    size_t base = (size_t)y * (SEQ * HD);
    int ss0 = blockIdx.x * 64;
    int t = threadIdx.x;
    #pragma unroll
    for (int c = t; c < 512; c += 256) {
        int r = c >> 3, col = (c & 7) * 8;
        *(uint4*)&tile[r][col] = *(const uint4*)&Vb[base + (size_t)(ss0 + r) * HD + col];
    }
    __syncthreads();
    #pragma unroll
    for (int c = t; c < 512; c += 256) {
        int dd = c >> 3, s8 = (c & 7) * 8;
        ushort4 a, bq;
        a.x = tile[s8 + 0][dd]; a.y = tile[s8 + 1][dd];
        a.z = tile[s8 + 2][dd]; a.w = tile[s8 + 3][dd];
        bq.x = tile[s8 + 4][dd]; bq.y = tile[s8 + 5][dd];
        bq.z = tile[s8 + 6][dd]; bq.w = tile[s8 + 7][dd];
        u16* dst = &Vtg[base + (size_t)dd * SEQ + ss0 + s8];
        *(ushort4*)dst = a;
        *(ushort4*)(dst + 4) = bq;
    }
}

// ---------------- GEMM: C[M][N] = A[M][K] * BT[N][K]^T + bias ----------------
// 128M x 64N tile, BK=64 (12 iters @ K=768), 256 threads (4 waves x 32M),
// register-prefetch pipeline. LDS stride 72 u16: 4-bank row rotation,
// conflict-free for b128 writes and fragment reads.
// EPI 0: bf16 Q, K (pre-scaled 0.125*log2e), V natural. EPI 1: fp32 out.
template <int EPI>
__global__ __launch_bounds__(256) void gemm_bt_kernel(
    const u16* __restrict__ A, const u16* __restrict__ BT,
    const float* __restrict__ bias,
    u16* __restrict__ outQ, u16* __restrict__ outK, u16* __restrict__ outV,
    float* __restrict__ outF,
    int M, int N, int K) {
    __shared__ u16 As[128 * 72];
    __shared__ u16 Bs[64 * 72];
    int tileM = blockIdx.y * 128, tileN = blockIdx.x * 64;
    int t = threadIdx.x;
    int lane = t & 63, wave = t >> 6;
    int wm = wave * 32;
    int quad = lane >> 4, l16 = lane & 15;
    f32x4 acc[2][4] = {};

    int rr = t >> 3, cc = (t & 7) * 8;      // 32 rows x 64 cols per pass
    const u16* Ag = A + (size_t)(tileM + rr) * K + cc;
    const u16* Bg = BT + (size_t)(tileN + rr) * K + cc;
    u16* AsW = &As[rr * 72 + cc];
    u16* BsW = &Bs[rr * 72 + cc];

    uint4 ra[4], rb[2];
    #pragma unroll
    for (int i = 0; i < 4; ++i) ra[i] = *(const uint4*)(Ag + (size_t)32 * i * K);
    #pragma unroll
    for (int i = 0; i < 2; ++i) rb[i] = *(const uint4*)(Bg + (size_t)32 * i * K);

    for (int k0 = 0; k0 < K; k0 += 64) {
        __syncthreads();
        #pragma unroll
        for (int i = 0; i < 4; ++i) *(uint4*)(AsW + i * 32 * 72) = ra[i];
        #pragma unroll
        for (int i = 0; i < 2; ++i) *(uint4*)(BsW + i * 32 * 72) = rb[i];
        __syncthreads();
        if (k0 + 64 < K) {
            #pragma unroll
            for (int i = 0; i < 4; ++i) ra[i] = *(const uint4*)(Ag + (size_t)32 * i * K + k0 + 64);
            #pragma unroll
            for (int i = 0; i < 2; ++i) rb[i] = *(const uint4*)(Bg + (size_t)32 * i * K + k0 + 64);
        }
        #pragma unroll
        for (int s = 0; s < 2; ++s) {
            bf16x8 af[2], bfr[4];
            #pragma unroll
            for (int i = 0; i < 2; ++i)
                af[i] = *(const bf16x8*)&As[(wm + i * 16 + l16) * 72 + s * 32 + quad * 8];
            #pragma unroll
            for (int j = 0; j < 4; ++j)
                bfr[j] = *(const bf16x8*)&Bs[(j * 16 + l16) * 72 + s * 32 + quad * 8];
            #pragma unroll
            for (int i = 0; i < 2; ++i)
                #pragma unroll
                for (int j = 0; j < 4; ++j)
                    acc[i][j] = __builtin_amdgcn_mfma_f32_16x16x32_bf16(af[i], bfr[j], acc[i][j], 0, 0, 0);
        }
    }

    #pragma unroll
    for (int i = 0; i < 2; ++i) {
        #pragma unroll
        for (int j = 0; j < 4; ++j) {
            int n = tileN + j * 16 + l16;
            float bv = bias[n];
            #pragma unroll
            for (int r = 0; r < 4; ++r) {
                int m = tileM + wm + i * 16 + quad * 4 + r;
                float v = acc[i][j][r] + bv;
                if (EPI == 0) {
                    if (n < 768) {
                        outQ[(size_t)m * 768 + n] = f2bf(v);
                    } else if (n < 1536) {
                        outK[(size_t)m * 768 + (n - 768)] = f2bf(v * (0.125f * LOG2E));
                    } else {
                        outV[(size_t)m * 768 + (n - 1536)] = f2bf(v);
                    }
                } else {
                    outF[(size_t)m * N + n] = v;
                }
            }
        }
    }
}

// ---------------- MFMA flash attention, split-K, fixed-max softmax ----------------
// grid (NCHUNK, BSZ*NHEAD), block 256: 4 waves x 32 q-rows (2 groups of 16).
// K/V fragment LDS reads amortized across both groups.
// Scores in base-2 domain (K pre-scaled 0.125*log2e, amask scaled log2e).
__global__ __launch_bounds__(256) void attn_mfma_kernel(
    const u16* __restrict__ Q, const u16* __restrict__ Kg,
    const u16* __restrict__ Vtg, const float* __restrict__ amask,
    u16* __restrict__ Opart, float* __restrict__ Lpart) {
    __shared__ u16 Ks[64][72];
    __shared__ u16 Vt[64][72];          // V^T tile: [d][key]
    __shared__ u16 Ps[4][2][16][72];    // per-wave, per-group P [q][key]
    __shared__ float Ams[64];

    int bh = blockIdx.y;
    int b = bh / NHEAD, h = bh % NHEAD;
    int p = NCHUNK - 1 - (int)blockIdx.x;   // heavy chunks dispatch first
    int bx = 15, c = 0, a = 0;
    #pragma unroll
    for (int i = 0; i < 16; ++i) {
        int n = (i >> 2) + 1;
        if (p < a + n) { bx = i; c = p - a; break; }
        a += n;
    }
    int kbase = c * 512;
    int nt = 2 * (bx + 1) - 8 * c;          // tiles of 64 keys in this chunk
    if (nt > 8) nt = 8;

    int t = threadIdx.x;
    int w = t >> 6, lane = t & 63;
    int quad = lane >> 4, l16 = lane & 15;
    size_t headbase = (size_t)b * (SEQ * NXC) + (size_t)h * (SEQ * HD);
    size_t headbaseT = (size_t)(b * NHEAD + h) * (SEQ * HD);

    int r0 = bx * 128;
    int qw0 = r0 + w * 32;                  // wave owns 32 q-rows (2 groups of 16)
    bf16x8 qf[2][2];
    #pragma unroll
    for (int g = 0; g < 2; ++g)
        #pragma unroll
        for (int s = 0; s < 2; ++s)
            qf[g][s] = *(const bf16x8*)&Q[headbase + (size_t)(qw0 + g * 16 + l16) * HD + s * 32 + quad * 8];

    float l_part[2] = {0.f, 0.f};
    f32x4 o[2][4] = {};

    // register prefetch of tile 0 (256 threads: 2 chunks each per 64x64 tile)
    int pr_row = t >> 3, pr_col = (t & 7) * 8;   // rows 0..31; +32 for chunk 2
    uint4 kr0, kr1, vr0, vr1; float amr;
    {
        int k0 = kbase;
        kr0 = *(const uint4*)&Kg[headbase + (size_t)(k0 + pr_row) * HD + pr_col];
        kr1 = *(const uint4*)&Kg[headbase + (size_t)(k0 + pr_row + 32) * HD + pr_col];
        vr0 = *(const uint4*)&Vtg[headbaseT + (size_t)pr_row * SEQ + k0 + pr_col];
        vr1 = *(const uint4*)&Vtg[headbaseT + (size_t)(pr_row + 32) * SEQ + k0 + pr_col];
        if (t < 64) amr = amask[(size_t)b * SEQ + k0 + t];
    }

    for (int kt = 0; kt < nt; ++kt) {
        int k0 = kbase + kt * 64;
        __syncthreads();
        *(uint4*)&Ks[pr_row][pr_col] = kr0;
        *(uint4*)&Ks[pr_row + 32][pr_col] = kr1;
        *(uint4*)&Vt[pr_row][pr_col] = vr0;
        *(uint4*)&Vt[pr_row + 32][pr_col] = vr1;
        if (t < 64) Ams[t] = amr * LOG2E;
        __syncthreads();
        if (kt + 1 < nt) {
            int kn = k0 + 64;
            kr0 = *(const uint4*)&Kg[headbase + (size_t)(kn + pr_row) * HD + pr_col];
            kr1 = *(const uint4*)&Kg[headbase + (size_t)(kn + pr_row + 32) * HD + pr_col];
            vr0 = *(const uint4*)&Vtg[headbaseT + (size_t)pr_row * SEQ + kn + pr_col];
            vr1 = *(const uint4*)&Vtg[headbaseT + (size_t)(pr_row + 32) * SEQ + kn + pr_col];
            if (t < 64) amr = amask[(size_t)b * SEQ + kn + t];
        }

        if (k0 > qw0 + 31) continue;        // wave fully past-causal
        bool act0 = (k0 <= qw0 + 15);       // group 0 active

        // K fragments + mask values, shared by both groups
        bf16x8 kf[2][4];
        #pragma unroll
        for (int s = 0; s < 2; ++s)
            #pragma unroll
            for (int j = 0; j < 4; ++j)
                kf[s][j] = *(const bf16x8*)&Ks[j * 16 + l16][s * 32 + quad * 8];
        float4 am4[4];
        #pragma unroll
        for (int j = 0; j < 4; ++j)
            am4[j] = *(const float4*)&Ams[j * 16 + quad * 4];

        #pragma unroll
        for (int g = 0; g < 2; ++g) {
            if (g == 0 && !act0) continue;
            int qg0 = qw0 + g * 16;
            int qrow = qg0 + l16;           // lane owns q-row (S^T layout)
            f32x4 sacc[4] = {};
            #pragma unroll
            for (int s = 0; s < 2; ++s)
                #pragma unroll
                for (int j = 0; j < 4; ++j)
                    sacc[j] = __builtin_amdgcn_mfma_f32_16x16x32_bf16(kf[s][j], qf[g][s], sacc[j], 0, 0, 0);

            bool diag = (k0 + 63 > qg0);
            #pragma unroll
            for (int j = 0; j < 4; ++j) {
                float pv[4];
                float am[4] = {am4[j].x, am4[j].y, am4[j].z, am4[j].w};
                #pragma unroll
                for (int r = 0; r < 4; ++r) {
                    float pp = ex2(sacc[j][r] + am[r]);
                    if (diag && (k0 + j * 16 + quad * 4 + r > qrow)) pp = 0.f;
                    pv[r] = pp;
                }
                l_part[g] += (pv[0] + pv[1]) + (pv[2] + pv[3]);
                unsigned pk01 = ((__float_as_uint(pv[0]) + 0x8000u) >> 16) |
                                ((__float_as_uint(pv[1]) + 0x8000u) & 0xffff0000u);
                unsigned pk23 = ((__float_as_uint(pv[2]) + 0x8000u) >> 16) |
                                ((__float_as_uint(pv[3]) + 0x8000u) & 0xffff0000u);
                *(uint2*)&Ps[w][g][l16][j * 16 + quad * 4] = make_uint2(pk01, pk23);
            }
        }

        // PV: O[q][d] += P[q][k] * Vt[d][k]^T ; V fragments shared across groups
        #pragma unroll
        for (int s = 0; s < 2; ++s) {
            bf16x8 pf1 = *(const bf16x8*)&Ps[w][1][l16][s * 32 + quad * 8];
            bf16x8 pf0;
            if (act0) pf0 = *(const bf16x8*)&Ps[w][0][l16][s * 32 + quad * 8];
            #pragma unroll
            for (int dc = 0; dc < 4; ++dc) {
                bf16x8 vf = *(const bf16x8*)&Vt[dc * 16 + l16][s * 32 + quad * 8];
                if (act0) o[0][dc] = __builtin_amdgcn_mfma_f32_16x16x32_bf16(pf0, vf, o[0][dc], 0, 0, 0);
                o[1][dc] = __builtin_amdgcn_mfma_f32_16x16x32_bf16(pf1, vf, o[1][dc], 0, 0, 0);
            }
        }
    }

    // epilogue: reduce l across quads, write unnormalized partials
    u16* Ob = Opart + ((size_t)bh * NCHUNK + p) * (128 * 64);
    float* Lb = Lpart + ((size_t)bh * NCHUNK + p) * 128;
    #pragma unroll
    for (int g = 0; g < 2; ++g) {
        float l = l_part[g] + __shfl_xor(l_part[g], 16);
        l += __shfl_xor(l, 32);
        #pragma unroll
        for (int dc = 0; dc < 4; ++dc)
            #pragma unroll
            for (int r = 0; r < 4; ++r) {
                int rl = w * 32 + g * 16 + quad * 4 + r;
                Ob[rl * 64 + dc * 16 + l16] = f2bf(o[g][dc][r]);
            }
        if (quad == 0) Lb[w * 32 + g * 16 + l16] = l;
    }
}

// ---------------- combine partials -> bf16 A (vectorized, high-parallelism) ----
// grid (SEQ/32, BSZ*NHEAD), block 256: each block does 32 rows x 64 dims.
__global__ __launch_bounds__(256) void attn_combine_kernel(
    const u16* __restrict__ Opart, const float* __restrict__ Lpart,
    u16* __restrict__ Aout) {
    __shared__ float winv[32];
    int bh = blockIdx.y;
    int b = bh / NHEAD, h = bh % NHEAD;
    int row0 = blockIdx.x * 32;             // global q-row base
    int bx = row0 >> 7;                     // 128-row q-tile
    int g = bx >> 2;
    int nch = g + 1;
    int p0 = 2 * g * (g + 1) + (bx & 3) * (g + 1);
    int rbase = row0 & 127;                 // row offset within the 128-tile
    int t = threadIdx.x;

    if (t < 32) {
        float L = 0.f;
        for (int c = 0; c < nch; ++c)
            L += Lpart[((size_t)bh * NCHUNK + p0 + c) * 128 + rbase + t];
        winv[t] = 1.0f / L;
    }
    __syncthreads();

    int row = t >> 3;                       // 0..31
    int d0 = (t & 7) * 8;
    int rl = rbase + row;
    float acc[8] = {};
    for (int c = 0; c < nch; ++c) {
        uint4 u = *(const uint4*)&Opart[(((size_t)bh * NCHUNK + p0 + c) * 128 + rl) * 64 + d0];
        acc[0] += __uint_as_float(u.x << 16);
        acc[1] += __uint_as_float(u.x & 0xffff0000u);
        acc[2] += __uint_as_float(u.y << 16);
        acc[3] += __uint_as_float(u.y & 0xffff0000u);
        acc[4] += __uint_as_float(u.z << 16);
        acc[5] += __uint_as_float(u.z & 0xffff0000u);
        acc[6] += __uint_as_float(u.w << 16);
        acc[7] += __uint_as_float(u.w & 0xffff0000u);
    }
    float s = winv[row];
    uint4 o;
    o.x = pk2(acc[0] * s, acc[1] * s);
    o.y = pk2(acc[2] * s, acc[3] * s);
    o.z = pk2(acc[4] * s, acc[5] * s);
    o.w = pk2(acc[6] * s, acc[7] * s);
    *(uint4*)&Aout[((size_t)b * SEQ + row0 + row) * NXC + h * HD + d0] = o;
}

// ---------------- launcher ----------------
extern "C" void kernel_launch(void* const* d_in, const int* in_sizes, int n_in,
                              void* d_out, int out_size, void* d_ws, size_t ws_size,
                              hipStream_t stream) {
    const float* hs     = (const float*)d_in[0];
    const float* amask  = (const float*)d_in[1];
    const float* w_attn = (const float*)d_in[2];
    const float* b_attn = (const float*)d_in[3];
    const float* w_proj = (const float*)d_in[4];
    const float* b_proj = (const float*)d_in[5];
    float* out = (float*)d_out;

    const int M = BSZ * SEQ;            // 4096
    char* ws = (char*)d_ws;
    auto alloc = [&](size_t bytes) {
        char* p = ws;
        ws += (bytes + 255) & ~(size_t)255;
        return p;
    };
    u16* HSbf   = (u16*)alloc((size_t)M * NXC * 2);
    u16* WaT    = (u16*)alloc((size_t)3 * NXC * NXC * 2);   // 2304 x 768
    u16* WpT    = (u16*)alloc((size_t)NXC * NXC * 2);       // 768 x 768
    u16* Qb     = (u16*)alloc((size_t)M * NXC * 2);
    u16* Kb     = (u16*)alloc((size_t)M * NXC * 2);
    u16* Vb     = (u16*)alloc((size_t)M * NXC * 2);         // natural
    u16* Vtg    = (u16*)alloc((size_t)M * NXC * 2);         // per-head [d][s]
    u16* Ab     = (u16*)alloc((size_t)M * NXC * 2);
    u16* Opart  = (u16*)alloc((size_t)BSZ * NHEAD * NCHUNK * 128 * 64 * 2);
    float* Lpart = (float*)alloc((size_t)BSZ * NHEAD * NCHUNK * 128 * 4);

    // prep
    {
        int n4 = M * NXC / 4;
        cast4_kernel<<<dim3((n4 + 255) / 256), dim3(256), 0, stream>>>(hs, HSbf, n4);
        transpose_cast_kernel<<<dim3(3 * NXC / 32, NXC / 32), dim3(32, 8), 0, stream>>>(w_attn, WaT, NXC, 3 * NXC);
        transpose_cast_kernel<<<dim3(NXC / 32, NXC / 32), dim3(32, 8), 0, stream>>>(w_proj, WpT, NXC, NXC);
    }
    // qkv gemm: M=4096, N=2304, K=768 -> bf16 Q/K/V natural (K pre-scaled)
    gemm_bt_kernel<0><<<dim3(3 * NXC / 64, M / 128), dim3(256), 0, stream>>>(
        HSbf, WaT, b_attn, Qb, Kb, Vb, nullptr, M, 3 * NXC, NXC);
    // per-head V transpose
    vt_kernel<<<dim3(SEQ / 64, BSZ * NHEAD), dim3(256), 0, stream>>>(Vb, Vtg);
    // attention: split-K partials, then combine
    attn_mfma_kernel<<<dim3(NCHUNK, BSZ * NHEAD), dim3(256), 0, stream>>>(
        Qb, Kb, Vtg, amask, Opart, Lpart);
    attn_combine_kernel<<<dim3(SEQ / 32, BSZ * NHEAD), dim3(256), 0, stream>>>(
        Opart, Lpart, Ab);
    // proj gemm: M=4096, N=768, K=768 -> d_out fp32
    gemm_bt_kernel<1><<<dim3(NXC / 64, M / 128), dim3(256), 0, stream>>>(
        Ab, WpT, b_proj, nullptr, nullptr, nullptr, out, M, NXC, NXC);
}

// Round 11
// 179.624 us; speedup vs baseline: 1.5824x; 1.5824x over previous
//
#include <hip/hip_runtime.h>
#include <hip/hip_bf16.h>

typedef unsigned short u16;
typedef short bf16x8 __attribute__((ext_vector_type(8)));
typedef float f32x4 __attribute__((ext_vector_type(4)));

#define NXC 768
#define NHEAD 12
#define SEQ 2048
#define BSZ 2
#define HD 64
#define NCHUNK 40   // sum over 16 q-tiles of ceil(128*(bx+1)/512)
#define LOG2E 1.4426950408889634f

__device__ inline u16 f2bf(float f) {
    unsigned int u = __float_as_uint(f);
    unsigned int r = u + 0x7fffu + ((u >> 16) & 1u);
    return (u16)(r >> 16);
}
__device__ inline unsigned pk2(float lo, float hi) {
    return (unsigned)f2bf(lo) | ((unsigned)f2bf(hi) << 16);
}
__device__ inline float ex2(float x) { return __builtin_amdgcn_exp2f(x); }

// ---------------- prep kernels ----------------
__global__ void cast4_kernel(const float* __restrict__ in, u16* __restrict__ out, int n4) {
    int i = blockIdx.x * 256 + threadIdx.x;
    if (i >= n4) return;
    float4 v = ((const float4*)in)[i];
    ushort4 o;
    o.x = f2bf(v.x); o.y = f2bf(v.y); o.z = f2bf(v.z); o.w = f2bf(v.w);
    ((ushort4*)out)[i] = o;
}

// out[C][R] = in[R][C], fp32 -> bf16
__global__ void transpose_cast_kernel(const float* __restrict__ in, u16* __restrict__ out,
                                      int R, int C) {
    __shared__ float tile[32][33];
    int cb = blockIdx.x * 32, rb = blockIdx.y * 32;
    int tx = threadIdx.x, ty = threadIdx.y;   // block (32,8)
    #pragma unroll
    for (int i = 0; i < 32; i += 8)
        tile[ty + i][tx] = in[(size_t)(rb + ty + i) * C + cb + tx];
    __syncthreads();
    #pragma unroll
    for (int i = 0; i < 32; i += 8)
        out[(size_t)(cb + ty + i) * R + rb + tx] = f2bf(tile[tx][ty + i]);
}

// per-head transpose: Vb head-chunk [ss][dd] -> Vtg [dd][ss] (both bf16)
__global__ __launch_bounds__(256) void vt_kernel(const u16* __restrict__ Vb,
                                                 u16* __restrict__ Vtg) {
    __shared__ u16 tile[64][68];
    int y = blockIdx.y;                        // b*NHEAD+h
    size_t base = (size_t)y * (SEQ * HD);
    int ss0 = blockIdx.x * 64;
    int t = threadIdx.x;
    #pragma unroll
    for (int c = t; c < 512; c += 256) {
        int r = c >> 3, col = (c & 7) * 8;
        *(uint4*)&tile[r][col] = *(const uint4*)&Vb[base + (size_t)(ss0 + r) * HD + col];
    }
    __syncthreads();
    #pragma unroll
    for (int c = t; c < 512; c += 256) {
        int dd = c >> 3, s8 = (c & 7) * 8;
        ushort4 a, bq;
        a.x = tile[s8 + 0][dd]; a.y = tile[s8 + 1][dd];
        a.z = tile[s8 + 2][dd]; a.w = tile[s8 + 3][dd];
        bq.x = tile[s8 + 4][dd]; bq.y = tile[s8 + 5][dd];
        bq.z = tile[s8 + 6][dd]; bq.w = tile[s8 + 7][dd];
        u16* dst = &Vtg[base + (size_t)dd * SEQ + ss0 + s8];
        *(ushort4*)dst = a;
        *(ushort4*)(dst + 4) = bq;
    }
}

// ---------------- GEMM: C[M][N] = A[M][K] * BT[N][K]^T + bias ----------------
// 128M x 64N tile, BK=32, 256 threads (4 waves x 32M x 64N), register-prefetch
// pipeline (3x uint4 — known spill-free at VGPR~72; BK=64/6x uint4 spilled).
// EPI 0: bf16 Q, K (pre-scaled 0.125*log2e), V natural. EPI 1: fp32 out[M][N].
template <int EPI>
__global__ __launch_bounds__(256) void gemm_bt_kernel(
    const u16* __restrict__ A, const u16* __restrict__ BT,
    const float* __restrict__ bias,
    u16* __restrict__ outQ, u16* __restrict__ outK, u16* __restrict__ outV,
    float* __restrict__ outF,
    int M, int N, int K) {
    __shared__ u16 As[128 * 32];
    __shared__ u16 Bs[64 * 32];
    int tileM = blockIdx.y * 128, tileN = blockIdx.x * 64;
    int t = threadIdx.x;
    int lane = t & 63, wave = t >> 6;
    int wm = wave * 32;
    int quad = lane >> 4, l16 = lane & 15;
    f32x4 acc[2][4] = {};

    int r0 = t >> 2, c0 = (t & 3) * 8;
    const u16* Ag0 = A + (size_t)(tileM + r0) * K + c0;
    const u16* Ag1 = Ag0 + (size_t)64 * K;
    const u16* Bg0 = BT + (size_t)(tileN + r0) * K + c0;   // r0 in 0..63
    u16* AsW0 = &As[r0 * 32 + c0];
    u16* AsW1 = &As[(r0 + 64) * 32 + c0];
    u16* BsW0 = &Bs[(r0 & 63) * 32 + c0];

    uint4 ra0 = *(const uint4*)(Ag0);
    uint4 ra1 = *(const uint4*)(Ag1);
    uint4 rb0 = *(const uint4*)(Bg0);

    for (int k0 = 0; k0 < K; k0 += 32) {
        __syncthreads();
        *(uint4*)AsW0 = ra0;
        *(uint4*)AsW1 = ra1;
        *(uint4*)BsW0 = rb0;
        __syncthreads();
        if (k0 + 32 < K) {
            ra0 = *(const uint4*)(Ag0 + k0 + 32);
            ra1 = *(const uint4*)(Ag1 + k0 + 32);
            rb0 = *(const uint4*)(Bg0 + k0 + 32);
        }
        bf16x8 af[2], bfr[4];
        #pragma unroll
        for (int i = 0; i < 2; ++i)
            af[i] = *(const bf16x8*)&As[(wm + i * 16 + l16) * 32 + quad * 8];
        #pragma unroll
        for (int j = 0; j < 4; ++j)
            bfr[j] = *(const bf16x8*)&Bs[(j * 16 + l16) * 32 + quad * 8];
        #pragma unroll
        for (int i = 0; i < 2; ++i)
            #pragma unroll
            for (int j = 0; j < 4; ++j)
                acc[i][j] = __builtin_amdgcn_mfma_f32_16x16x32_bf16(af[i], bfr[j], acc[i][j], 0, 0, 0);
    }

    #pragma unroll
    for (int i = 0; i < 2; ++i) {
        #pragma unroll
        for (int j = 0; j < 4; ++j) {
            int n = tileN + j * 16 + l16;
            float bv = bias[n];
            #pragma unroll
            for (int r = 0; r < 4; ++r) {
                int m = tileM + wm + i * 16 + quad * 4 + r;
                float v = acc[i][j][r] + bv;
                if (EPI == 0) {
                    if (n < 768) {
                        outQ[(size_t)m * 768 + n] = f2bf(v);
                    } else if (n < 1536) {
                        outK[(size_t)m * 768 + (n - 768)] = f2bf(v * (0.125f * LOG2E));
                    } else {
                        outV[(size_t)m * 768 + (n - 1536)] = f2bf(v);
                    }
                } else {
                    outF[(size_t)m * N + n] = v;
                }
            }
        }
    }
}

// ---------------- MFMA flash attention, split-K, fixed-max softmax ----------------
// grid (NCHUNK, BSZ*NHEAD), block 256: 4 waves x 32 q-rows (2 groups of 16).
// K/V fragment LDS reads amortized across both groups.
// Scores in base-2 domain (K pre-scaled 0.125*log2e, amask scaled log2e).
__global__ __launch_bounds__(256) void attn_mfma_kernel(
    const u16* __restrict__ Q, const u16* __restrict__ Kg,
    const u16* __restrict__ Vtg, const float* __restrict__ amask,
    u16* __restrict__ Opart, float* __restrict__ Lpart) {
    __shared__ u16 Ks[64][72];
    __shared__ u16 Vt[64][72];          // V^T tile: [d][key]
    __shared__ u16 Ps[4][2][16][72];    // per-wave, per-group P [q][key]
    __shared__ float Ams[64];

    int bh = blockIdx.y;
    int b = bh / NHEAD, h = bh % NHEAD;
    int p = NCHUNK - 1 - (int)blockIdx.x;   // heavy chunks dispatch first
    int bx = 15, c = 0, a = 0;
    #pragma unroll
    for (int i = 0; i < 16; ++i) {
        int n = (i >> 2) + 1;
        if (p < a + n) { bx = i; c = p - a; break; }
        a += n;
    }
    int kbase = c * 512;
    int nt = 2 * (bx + 1) - 8 * c;          // tiles of 64 keys in this chunk
    if (nt > 8) nt = 8;

    int t = threadIdx.x;
    int w = t >> 6, lane = t & 63;
    int quad = lane >> 4, l16 = lane & 15;
    size_t headbase = (size_t)b * (SEQ * NXC) + (size_t)h * (SEQ * HD);
    size_t headbaseT = (size_t)(b * NHEAD + h) * (SEQ * HD);

    int r0 = bx * 128;
    int qw0 = r0 + w * 32;                  // wave owns 32 q-rows (2 groups of 16)
    bf16x8 qf[2][2];
    #pragma unroll
    for (int g = 0; g < 2; ++g)
        #pragma unroll
        for (int s = 0; s < 2; ++s)
            qf[g][s] = *(const bf16x8*)&Q[headbase + (size_t)(qw0 + g * 16 + l16) * HD + s * 32 + quad * 8];

    float l_part[2] = {0.f, 0.f};
    f32x4 o[2][4] = {};

    // register prefetch of tile 0 (256 threads: 2 chunks each per 64x64 tile)
    int pr_row = t >> 3, pr_col = (t & 7) * 8;   // rows 0..31; +32 for chunk 2
    uint4 kr0, kr1, vr0, vr1; float amr;
    {
        int k0 = kbase;
        kr0 = *(const uint4*)&Kg[headbase + (size_t)(k0 + pr_row) * HD + pr_col];
        kr1 = *(const uint4*)&Kg[headbase + (size_t)(k0 + pr_row + 32) * HD + pr_col];
        vr0 = *(const uint4*)&Vtg[headbaseT + (size_t)pr_row * SEQ + k0 + pr_col];
        vr1 = *(const uint4*)&Vtg[headbaseT + (size_t)(pr_row + 32) * SEQ + k0 + pr_col];
        if (t < 64) amr = amask[(size_t)b * SEQ + k0 + t];
    }

    for (int kt = 0; kt < nt; ++kt) {
        int k0 = kbase + kt * 64;
        __syncthreads();
        *(uint4*)&Ks[pr_row][pr_col] = kr0;
        *(uint4*)&Ks[pr_row + 32][pr_col] = kr1;
        *(uint4*)&Vt[pr_row][pr_col] = vr0;
        *(uint4*)&Vt[pr_row + 32][pr_col] = vr1;
        if (t < 64) Ams[t] = amr * LOG2E;
        __syncthreads();
        if (kt + 1 < nt) {
            int kn = k0 + 64;
            kr0 = *(const uint4*)&Kg[headbase + (size_t)(kn + pr_row) * HD + pr_col];
            kr1 = *(const uint4*)&Kg[headbase + (size_t)(kn + pr_row + 32) * HD + pr_col];
            vr0 = *(const uint4*)&Vtg[headbaseT + (size_t)pr_row * SEQ + kn + pr_col];
            vr1 = *(const uint4*)&Vtg[headbaseT + (size_t)(pr_row + 32) * SEQ + kn + pr_col];
            if (t < 64) amr = amask[(size_t)b * SEQ + kn + t];
        }

        if (k0 > qw0 + 31) continue;        // wave fully past-causal
        bool act0 = (k0 <= qw0 + 15);       // group 0 active

        // K fragments + mask values, shared by both groups
        bf16x8 kf[2][4];
        #pragma unroll
        for (int s = 0; s < 2; ++s)
            #pragma unroll
            for (int j = 0; j < 4; ++j)
                kf[s][j] = *(const bf16x8*)&Ks[j * 16 + l16][s * 32 + quad * 8];
        float4 am4[4];
        #pragma unroll
        for (int j = 0; j < 4; ++j)
            am4[j] = *(const float4*)&Ams[j * 16 + quad * 4];

        #pragma unroll
        for (int g = 0; g < 2; ++g) {
            if (g == 0 && !act0) continue;
            int qg0 = qw0 + g * 16;
            int qrow = qg0 + l16;           // lane owns q-row (S^T layout)
            f32x4 sacc[4] = {};
            #pragma unroll
            for (int s = 0; s < 2; ++s)
                #pragma unroll
                for (int j = 0; j < 4; ++j)
                    sacc[j] = __builtin_amdgcn_mfma_f32_16x16x32_bf16(kf[s][j], qf[g][s], sacc[j], 0, 0, 0);

            bool diag = (k0 + 63 > qg0);
            #pragma unroll
            for (int j = 0; j < 4; ++j) {
                float pv[4];
                float am[4] = {am4[j].x, am4[j].y, am4[j].z, am4[j].w};
                #pragma unroll
                for (int r = 0; r < 4; ++r) {
                    float pp = ex2(sacc[j][r] + am[r]);
                    if (diag && (k0 + j * 16 + quad * 4 + r > qrow)) pp = 0.f;
                    pv[r] = pp;
                }
                l_part[g] += (pv[0] + pv[1]) + (pv[2] + pv[3]);
                unsigned pk01 = ((__float_as_uint(pv[0]) + 0x8000u) >> 16) |
                                ((__float_as_uint(pv[1]) + 0x8000u) & 0xffff0000u);
                unsigned pk23 = ((__float_as_uint(pv[2]) + 0x8000u) >> 16) |
                                ((__float_as_uint(pv[3]) + 0x8000u) & 0xffff0000u);
                *(uint2*)&Ps[w][g][l16][j * 16 + quad * 4] = make_uint2(pk01, pk23);
            }
        }

        // PV: O[q][d] += P[q][k] * Vt[d][k]^T ; V fragments shared across groups
        #pragma unroll
        for (int s = 0; s < 2; ++s) {
            bf16x8 pf1 = *(const bf16x8*)&Ps[w][1][l16][s * 32 + quad * 8];
            bf16x8 pf0;
            if (act0) pf0 = *(const bf16x8*)&Ps[w][0][l16][s * 32 + quad * 8];
            #pragma unroll
            for (int dc = 0; dc < 4; ++dc) {
                bf16x8 vf = *(const bf16x8*)&Vt[dc * 16 + l16][s * 32 + quad * 8];
                if (act0) o[0][dc] = __builtin_amdgcn_mfma_f32_16x16x32_bf16(pf0, vf, o[0][dc], 0, 0, 0);
                o[1][dc] = __builtin_amdgcn_mfma_f32_16x16x32_bf16(pf1, vf, o[1][dc], 0, 0, 0);
            }
        }
    }

    // epilogue: reduce l across quads, write unnormalized partials
    u16* Ob = Opart + ((size_t)bh * NCHUNK + p) * (128 * 64);
    float* Lb = Lpart + ((size_t)bh * NCHUNK + p) * 128;
    #pragma unroll
    for (int g = 0; g < 2; ++g) {
        float l = l_part[g] + __shfl_xor(l_part[g], 16);
        l += __shfl_xor(l, 32);
        #pragma unroll
        for (int dc = 0; dc < 4; ++dc)
            #pragma unroll
            for (int r = 0; r < 4; ++r) {
                int rl = w * 32 + g * 16 + quad * 4 + r;
                Ob[rl * 64 + dc * 16 + l16] = f2bf(o[g][dc][r]);
            }
        if (quad == 0) Lb[w * 32 + g * 16 + l16] = l;
    }
}

// ---------------- combine partials -> bf16 A (vectorized, high-parallelism) ----
// grid (SEQ/32, BSZ*NHEAD), block 256: each block does 32 rows x 64 dims.
__global__ __launch_bounds__(256) void attn_combine_kernel(
    const u16* __restrict__ Opart, const float* __restrict__ Lpart,
    u16* __restrict__ Aout) {
    __shared__ float winv[32];
    int bh = blockIdx.y;
    int b = bh / NHEAD, h = bh % NHEAD;
    int row0 = blockIdx.x * 32;             // global q-row base
    int bx = row0 >> 7;                     // 128-row q-tile
    int g = bx >> 2;
    int nch = g + 1;
    int p0 = 2 * g * (g + 1) + (bx & 3) * (g + 1);
    int rbase = row0 & 127;                 // row offset within the 128-tile
    int t = threadIdx.x;

    if (t < 32) {
        float L = 0.f;
        for (int c = 0; c < nch; ++c)
            L += Lpart[((size_t)bh * NCHUNK + p0 + c) * 128 + rbase + t];
        winv[t] = 1.0f / L;
    }
    __syncthreads();

    int row = t >> 3;                       // 0..31
    int d0 = (t & 7) * 8;
    int rl = rbase + row;
    float acc[8] = {};
    for (int c = 0; c < nch; ++c) {
        uint4 u = *(const uint4*)&Opart[(((size_t)bh * NCHUNK + p0 + c) * 128 + rl) * 64 + d0];
        acc[0] += __uint_as_float(u.x << 16);
        acc[1] += __uint_as_float(u.x & 0xffff0000u);
        acc[2] += __uint_as_float(u.y << 16);
        acc[3] += __uint_as_float(u.y & 0xffff0000u);
        acc[4] += __uint_as_float(u.z << 16);
        acc[5] += __uint_as_float(u.z & 0xffff0000u);
        acc[6] += __uint_as_float(u.w << 16);
        acc[7] += __uint_as_float(u.w & 0xffff0000u);
    }
    float s = winv[row];
    uint4 o;
    o.x = pk2(acc[0] * s, acc[1] * s);
    o.y = pk2(acc[2] * s, acc[3] * s);
    o.z = pk2(acc[4] * s, acc[5] * s);
    o.w = pk2(acc[6] * s, acc[7] * s);
    *(uint4*)&Aout[((size_t)b * SEQ + row0 + row) * NXC + h * HD + d0] = o;
}

// ---------------- launcher ----------------
extern "C" void kernel_launch(void* const* d_in, const int* in_sizes, int n_in,
                              void* d_out, int out_size, void* d_ws, size_t ws_size,
                              hipStream_t stream) {
    const float* hs     = (const float*)d_in[0];
    const float* amask  = (const float*)d_in[1];
    const float* w_attn = (const float*)d_in[2];
    const float* b_attn = (const float*)d_in[3];
    const float* w_proj = (const float*)d_in[4];
    const float* b_proj = (const float*)d_in[5];
    float* out = (float*)d_out;

    const int M = BSZ * SEQ;            // 4096
    char* ws = (char*)d_ws;
    auto alloc = [&](size_t bytes) {
        char* p = ws;
        ws += (bytes + 255) & ~(size_t)255;
        return p;
    };
    u16* HSbf   = (u16*)alloc((size_t)M * NXC * 2);
    u16* WaT    = (u16*)alloc((size_t)3 * NXC * NXC * 2);   // 2304 x 768
    u16* WpT    = (u16*)alloc((size_t)NXC * NXC * 2);       // 768 x 768
    u16* Qb     = (u16*)alloc((size_t)M * NXC * 2);
    u16* Kb     = (u16*)alloc((size_t)M * NXC * 2);
    u16* Vb     = (u16*)alloc((size_t)M * NXC * 2);         // natural
    u16* Vtg    = (u16*)alloc((size_t)M * NXC * 2);         // per-head [d][s]
    u16* Ab     = (u16*)alloc((size_t)M * NXC * 2);
    u16* Opart  = (u16*)alloc((size_t)BSZ * NHEAD * NCHUNK * 128 * 64 * 2);
    float* Lpart = (float*)alloc((size_t)BSZ * NHEAD * NCHUNK * 128 * 4);

    // prep
    {
        int n4 = M * NXC / 4;
        cast4_kernel<<<dim3((n4 + 255) / 256), dim3(256), 0, stream>>>(hs, HSbf, n4);
        transpose_cast_kernel<<<dim3(3 * NXC / 32, NXC / 32), dim3(32, 8), 0, stream>>>(w_attn, WaT, NXC, 3 * NXC);
        transpose_cast_kernel<<<dim3(NXC / 32, NXC / 32), dim3(32, 8), 0, stream>>>(w_proj, WpT, NXC, NXC);
    }
    // qkv gemm: M=4096, N=2304, K=768 -> bf16 Q/K/V natural (K pre-scaled)
    gemm_bt_kernel<0><<<dim3(3 * NXC / 64, M / 128), dim3(256), 0, stream>>>(
        HSbf, WaT, b_attn, Qb, Kb, Vb, nullptr, M, 3 * NXC, NXC);
    // per-head V transpose
    vt_kernel<<<dim3(SEQ / 64, BSZ * NHEAD), dim3(256), 0, stream>>>(Vb, Vtg);
    // attention: split-K partials, then combine
    attn_mfma_kernel<<<dim3(NCHUNK, BSZ * NHEAD), dim3(256), 0, stream>>>(
        Qb, Kb, Vtg, amask, Opart, Lpart);
    attn_combine_kernel<<<dim3(SEQ / 32, BSZ * NHEAD), dim3(256), 0, stream>>>(
        Opart, Lpart, Ab);
    // proj gemm: M=4096, N=768, K=768 -> d_out fp32
    gemm_bt_kernel<1><<<dim3(NXC / 64, M / 128), dim3(256), 0, stream>>>(
        Ab, WpT, b_proj, nullptr, nullptr, nullptr, out, M, NXC, NXC);
}

// Round 12
// 173.844 us; speedup vs baseline: 1.6350x; 1.0332x over previous
//
#include <hip/hip_runtime.h>
#include <hip/hip_bf16.h>

typedef unsigned short u16;
typedef short bf16x8 __attribute__((ext_vector_type(8)));
typedef float f32x4 __attribute__((ext_vector_type(4)));

#define NXC 768
#define NHEAD 12
#define SEQ 2048
#define BSZ 2
#define HD 64
#define NCHUNK 40   // sum over 16 q-tiles of ceil(128*(bx+1)/512)
#define LOG2E 1.4426950408889634f

__device__ inline u16 f2bf(float f) {
    unsigned int u = __float_as_uint(f);
    unsigned int r = u + 0x7fffu + ((u >> 16) & 1u);
    return (u16)(r >> 16);
}
__device__ inline unsigned pk2(float lo, float hi) {
    return (unsigned)f2bf(lo) | ((unsigned)f2bf(hi) << 16);
}
__device__ inline float ex2(float x) { return __builtin_amdgcn_exp2f(x); }

// ---------------- prep kernels ----------------
__global__ void cast4_kernel(const float* __restrict__ in, u16* __restrict__ out, int n4) {
    int i = blockIdx.x * 256 + threadIdx.x;
    if (i >= n4) return;
    float4 v = ((const float4*)in)[i];
    ushort4 o;
    o.x = f2bf(v.x); o.y = f2bf(v.y); o.z = f2bf(v.z); o.w = f2bf(v.w);
    ((ushort4*)out)[i] = o;
}

// out[C][R] = in[R][C], fp32 -> bf16
__global__ void transpose_cast_kernel(const float* __restrict__ in, u16* __restrict__ out,
                                      int R, int C) {
    __shared__ float tile[32][33];
    int cb = blockIdx.x * 32, rb = blockIdx.y * 32;
    int tx = threadIdx.x, ty = threadIdx.y;   // block (32,8)
    #pragma unroll
    for (int i = 0; i < 32; i += 8)
        tile[ty + i][tx] = in[(size_t)(rb + ty + i) * C + cb + tx];
    __syncthreads();
    #pragma unroll
    for (int i = 0; i < 32; i += 8)
        out[(size_t)(cb + ty + i) * R + rb + tx] = f2bf(tile[tx][ty + i]);
}

// per-head transpose: Vb head-chunk [ss][dd] -> Vtg [dd][ss] (both bf16)
__global__ __launch_bounds__(256) void vt_kernel(const u16* __restrict__ Vb,
                                                 u16* __restrict__ Vtg) {
    __shared__ u16 tile[64][68];
    int y = blockIdx.y;                        // b*NHEAD+h
    size_t base = (size_t)y * (SEQ * HD);
    int ss0 = blockIdx.x * 64;
    int t = threadIdx.x;
    #pragma unroll
    for (int c = t; c < 512; c += 256) {
        int r = c >> 3, col = (c & 7) * 8;
        *(uint4*)&tile[r][col] = *(const uint4*)&Vb[base + (size_t)(ss0 + r) * HD + col];
    }
    __syncthreads();
    #pragma unroll
    for (int c = t; c < 512; c += 256) {
        int dd = c >> 3, s8 = (c & 7) * 8;
        ushort4 a, bq;
        a.x = tile[s8 + 0][dd]; a.y = tile[s8 + 1][dd];
        a.z = tile[s8 + 2][dd]; a.w = tile[s8 + 3][dd];
        bq.x = tile[s8 + 4][dd]; bq.y = tile[s8 + 5][dd];
        bq.z = tile[s8 + 6][dd]; bq.w = tile[s8 + 7][dd];
        u16* dst = &Vtg[base + (size_t)dd * SEQ + ss0 + s8];
        *(ushort4*)dst = a;
        *(ushort4*)(dst + 4) = bq;
    }
}

// ---------------- GEMM: C[M][N] = A[M][K] * BT[N][K]^T + bias ----------------
// 128M x 64N tile, BK=32, 256 threads (4 waves x 32M x 64N), register-prefetch
// pipeline (3x uint4 — known spill-free at VGPR~44/72; BK=64/6x uint4 spilled).
// EPI 0: bf16 Q, K (pre-scaled 0.125*log2e), V natural. EPI 1: fp32 out[M][N].
template <int EPI>
__global__ __launch_bounds__(256) void gemm_bt_kernel(
    const u16* __restrict__ A, const u16* __restrict__ BT,
    const float* __restrict__ bias,
    u16* __restrict__ outQ, u16* __restrict__ outK, u16* __restrict__ outV,
    float* __restrict__ outF,
    int M, int N, int K) {
    __shared__ u16 As[128 * 32];
    __shared__ u16 Bs[64 * 32];
    int tileM = blockIdx.y * 128, tileN = blockIdx.x * 64;
    int t = threadIdx.x;
    int lane = t & 63, wave = t >> 6;
    int wm = wave * 32;
    int quad = lane >> 4, l16 = lane & 15;
    f32x4 acc[2][4] = {};

    int r0 = t >> 2, c0 = (t & 3) * 8;
    const u16* Ag0 = A + (size_t)(tileM + r0) * K + c0;
    const u16* Ag1 = Ag0 + (size_t)64 * K;
    const u16* Bg0 = BT + (size_t)(tileN + r0) * K + c0;   // r0 in 0..63
    u16* AsW0 = &As[r0 * 32 + c0];
    u16* AsW1 = &As[(r0 + 64) * 32 + c0];
    u16* BsW0 = &Bs[(r0 & 63) * 32 + c0];

    uint4 ra0 = *(const uint4*)(Ag0);
    uint4 ra1 = *(const uint4*)(Ag1);
    uint4 rb0 = *(const uint4*)(Bg0);

    for (int k0 = 0; k0 < K; k0 += 32) {
        __syncthreads();
        *(uint4*)AsW0 = ra0;
        *(uint4*)AsW1 = ra1;
        *(uint4*)BsW0 = rb0;
        __syncthreads();
        if (k0 + 32 < K) {
            ra0 = *(const uint4*)(Ag0 + k0 + 32);
            ra1 = *(const uint4*)(Ag1 + k0 + 32);
            rb0 = *(const uint4*)(Bg0 + k0 + 32);
        }
        bf16x8 af[2], bfr[4];
        #pragma unroll
        for (int i = 0; i < 2; ++i)
            af[i] = *(const bf16x8*)&As[(wm + i * 16 + l16) * 32 + quad * 8];
        #pragma unroll
        for (int j = 0; j < 4; ++j)
            bfr[j] = *(const bf16x8*)&Bs[(j * 16 + l16) * 32 + quad * 8];
        #pragma unroll
        for (int i = 0; i < 2; ++i)
            #pragma unroll
            for (int j = 0; j < 4; ++j)
                acc[i][j] = __builtin_amdgcn_mfma_f32_16x16x32_bf16(af[i], bfr[j], acc[i][j], 0, 0, 0);
    }

    #pragma unroll
    for (int i = 0; i < 2; ++i) {
        #pragma unroll
        for (int j = 0; j < 4; ++j) {
            int n = tileN + j * 16 + l16;
            float bv = bias[n];
            #pragma unroll
            for (int r = 0; r < 4; ++r) {
                int m = tileM + wm + i * 16 + quad * 4 + r;
                float v = acc[i][j][r] + bv;
                if (EPI == 0) {
                    if (n < 768) {
                        outQ[(size_t)m * 768 + n] = f2bf(v);
                    } else if (n < 1536) {
                        outK[(size_t)m * 768 + (n - 768)] = f2bf(v * (0.125f * LOG2E));
                    } else {
                        outV[(size_t)m * 768 + (n - 1536)] = f2bf(v);
                    }
                } else {
                    outF[(size_t)m * N + n] = v;
                }
            }
        }
    }
}

// ---------------- MFMA flash attention, split-K, fixed-max softmax ----------------
// grid (NCHUNK, BSZ*NHEAD), block 512: 8 waves x 16 q-rows. (256-thread 2-group
// variant measured SLOWER: occupancy 12.5% vs 26.5% — wave count beats reuse.)
// Scores in base-2 domain (K pre-scaled 0.125*log2e, amask scaled log2e).
__global__ __launch_bounds__(512) void attn_mfma_kernel(
    const u16* __restrict__ Q, const u16* __restrict__ Kg,
    const u16* __restrict__ Vtg, const float* __restrict__ amask,
    u16* __restrict__ Opart, float* __restrict__ Lpart) {
    __shared__ u16 Ks[64][72];
    __shared__ u16 Vt[64][72];          // V^T tile: [d][key]
    __shared__ u16 Ps[8][16][72];       // per-wave P [q][key]
    __shared__ float Ams[64];

    int bh = blockIdx.y;
    int b = bh / NHEAD, h = bh % NHEAD;
    int p = NCHUNK - 1 - (int)blockIdx.x;   // heavy chunks dispatch first
    int bx = 15, c = 0, a = 0;
    #pragma unroll
    for (int i = 0; i < 16; ++i) {
        int n = (i >> 2) + 1;
        if (p < a + n) { bx = i; c = p - a; break; }
        a += n;
    }
    int kbase = c * 512;
    int nt = 2 * (bx + 1) - 8 * c;          // tiles of 64 keys in this chunk
    if (nt > 8) nt = 8;

    int t = threadIdx.x;
    int w = t >> 6, lane = t & 63;
    int quad = lane >> 4, l16 = lane & 15;
    size_t headbase = (size_t)b * (SEQ * NXC) + (size_t)h * (SEQ * HD);
    size_t headbaseT = (size_t)(b * NHEAD + h) * (SEQ * HD);

    int r0 = bx * 128;
    int qw0 = r0 + w * 16;                  // wave owns 16 q-rows
    int qrow = qw0 + l16;
    bf16x8 qf[2];
    #pragma unroll
    for (int s = 0; s < 2; ++s)
        qf[s] = *(const bf16x8*)&Q[headbase + (size_t)(qw0 + l16) * HD + s * 32 + quad * 8];

    float l_part = 0.f;                     // per-lane partial of l
    f32x4 o[4] = {};

    // register prefetch of tile 0 (512 threads cover 64x64 K and V^T tiles)
    int pr_row = t >> 3, pr_col = (t & 7) * 8;
    uint4 kr, vr; float amr;
    {
        int k0 = kbase;
        kr = *(const uint4*)&Kg[headbase + (size_t)(k0 + pr_row) * HD + pr_col];
        vr = *(const uint4*)&Vtg[headbaseT + (size_t)pr_row * SEQ + k0 + pr_col];
        if (t < 64) amr = amask[(size_t)b * SEQ + k0 + t];
    }

    for (int kt = 0; kt < nt; ++kt) {
        int k0 = kbase + kt * 64;
        __syncthreads();
        *(uint4*)&Ks[pr_row][pr_col] = kr;
        *(uint4*)&Vt[pr_row][pr_col] = vr;
        if (t < 64) Ams[t] = amr * LOG2E;
        __syncthreads();
        if (kt + 1 < nt) {
            int kn = k0 + 64;
            kr = *(const uint4*)&Kg[headbase + (size_t)(kn + pr_row) * HD + pr_col];
            vr = *(const uint4*)&Vtg[headbaseT + (size_t)pr_row * SEQ + kn + pr_col];
            if (t < 64) amr = amask[(size_t)b * SEQ + kn + t];
        }

        if (k0 > qw0 + 15) continue;        // tile fully past-causal for this wave

        bf16x8 kf[2][4];
        #pragma unroll
        for (int s = 0; s < 2; ++s)
            #pragma unroll
            for (int j = 0; j < 4; ++j)
                kf[s][j] = *(const bf16x8*)&Ks[j * 16 + l16][s * 32 + quad * 8];
        float amv[4][4];
        #pragma unroll
        for (int j = 0; j < 4; ++j)
            #pragma unroll
            for (int r = 0; r < 4; ++r)
                amv[j][r] = Ams[j * 16 + quad * 4 + r];

        // S^T = K * Q^T : lane owns q-row = l16
        f32x4 sacc[4] = {};
        #pragma unroll
        for (int s = 0; s < 2; ++s)
            #pragma unroll
            for (int j = 0; j < 4; ++j)
                sacc[j] = __builtin_amdgcn_mfma_f32_16x16x32_bf16(kf[s][j], qf[s], sacc[j], 0, 0, 0);

        bool diag = (k0 + 63 > qw0);
        #pragma unroll
        for (int j = 0; j < 4; ++j) {
            float pv[4];
            #pragma unroll
            for (int r = 0; r < 4; ++r) {
                float pp = ex2(sacc[j][r] + amv[j][r]);
                if (diag && (k0 + j * 16 + quad * 4 + r > qrow)) pp = 0.f;
                pv[r] = pp;
            }
            l_part += (pv[0] + pv[1]) + (pv[2] + pv[3]);
            unsigned pk01 = ((__float_as_uint(pv[0]) + 0x8000u) >> 16) |
                            ((__float_as_uint(pv[1]) + 0x8000u) & 0xffff0000u);
            unsigned pk23 = ((__float_as_uint(pv[2]) + 0x8000u) >> 16) |
                            ((__float_as_uint(pv[3]) + 0x8000u) & 0xffff0000u);
            *(uint2*)&Ps[w][l16][j * 16 + quad * 4] = make_uint2(pk01, pk23);
        }

        // PV: O[q][d] += P[q][k] * Vt[d][k]^T   (no rescale — fixed m)
        #pragma unroll
        for (int s = 0; s < 2; ++s) {
            bf16x8 pf = *(const bf16x8*)&Ps[w][l16][s * 32 + quad * 8];
            #pragma unroll
            for (int dc = 0; dc < 4; ++dc) {
                bf16x8 vf = *(const bf16x8*)&Vt[dc * 16 + l16][s * 32 + quad * 8];
                o[dc] = __builtin_amdgcn_mfma_f32_16x16x32_bf16(pf, vf, o[dc], 0, 0, 0);
            }
        }
    }

    // epilogue: reduce l across quads once, write unnormalized partials
    float l = l_part + __shfl_xor(l_part, 16);
    l += __shfl_xor(l, 32);
    u16* Ob = Opart + ((size_t)bh * NCHUNK + p) * (128 * 64);
    float* Lb = Lpart + ((size_t)bh * NCHUNK + p) * 128;
    #pragma unroll
    for (int dc = 0; dc < 4; ++dc)
        #pragma unroll
        for (int r = 0; r < 4; ++r) {
            int rl = w * 16 + quad * 4 + r;
            Ob[rl * 64 + dc * 16 + l16] = f2bf(o[dc][r]);
        }
    if (quad == 0) Lb[w * 16 + l16] = l;
}

// ---------------- combine partials -> bf16 A (vectorized, high-parallelism) ----
// grid (SEQ/32, BSZ*NHEAD), block 256: each block does 32 rows x 64 dims.
__global__ __launch_bounds__(256) void attn_combine_kernel(
    const u16* __restrict__ Opart, const float* __restrict__ Lpart,
    u16* __restrict__ Aout) {
    __shared__ float winv[32];
    int bh = blockIdx.y;
    int b = bh / NHEAD, h = bh % NHEAD;
    int row0 = blockIdx.x * 32;             // global q-row base
    int bx = row0 >> 7;                     // 128-row q-tile
    int g = bx >> 2;
    int nch = g + 1;
    int p0 = 2 * g * (g + 1) + (bx & 3) * (g + 1);
    int rbase = row0 & 127;                 // row offset within the 128-tile
    int t = threadIdx.x;

    if (t < 32) {
        float L = 0.f;
        for (int c = 0; c < nch; ++c)
            L += Lpart[((size_t)bh * NCHUNK + p0 + c) * 128 + rbase + t];
        winv[t] = 1.0f / L;
    }
    __syncthreads();

    int row = t >> 3;                       // 0..31
    int d0 = (t & 7) * 8;
    int rl = rbase + row;
    float acc[8] = {};
    for (int c = 0; c < nch; ++c) {
        uint4 u = *(const uint4*)&Opart[(((size_t)bh * NCHUNK + p0 + c) * 128 + rl) * 64 + d0];
        acc[0] += __uint_as_float(u.x << 16);
        acc[1] += __uint_as_float(u.x & 0xffff0000u);
        acc[2] += __uint_as_float(u.y << 16);
        acc[3] += __uint_as_float(u.y & 0xffff0000u);
        acc[4] += __uint_as_float(u.z << 16);
        acc[5] += __uint_as_float(u.z & 0xffff0000u);
        acc[6] += __uint_as_float(u.w << 16);
        acc[7] += __uint_as_float(u.w & 0xffff0000u);
    }
    float s = winv[row];
    uint4 o;
    o.x = pk2(acc[0] * s, acc[1] * s);
    o.y = pk2(acc[2] * s, acc[3] * s);
    o.z = pk2(acc[4] * s, acc[5] * s);
    o.w = pk2(acc[6] * s, acc[7] * s);
    *(uint4*)&Aout[((size_t)b * SEQ + row0 + row) * NXC + h * HD + d0] = o;
}

// ---------------- launcher ----------------
extern "C" void kernel_launch(void* const* d_in, const int* in_sizes, int n_in,
                              void* d_out, int out_size, void* d_ws, size_t ws_size,
                              hipStream_t stream) {
    const float* hs     = (const float*)d_in[0];
    const float* amask  = (const float*)d_in[1];
    const float* w_attn = (const float*)d_in[2];
    const float* b_attn = (const float*)d_in[3];
    const float* w_proj = (const float*)d_in[4];
    const float* b_proj = (const float*)d_in[5];
    float* out = (float*)d_out;

    const int M = BSZ * SEQ;            // 4096
    char* ws = (char*)d_ws;
    auto alloc = [&](size_t bytes) {
        char* p = ws;
        ws += (bytes + 255) & ~(size_t)255;
        return p;
    };
    u16* HSbf   = (u16*)alloc((size_t)M * NXC * 2);
    u16* WaT    = (u16*)alloc((size_t)3 * NXC * NXC * 2);   // 2304 x 768
    u16* WpT    = (u16*)alloc((size_t)NXC * NXC * 2);       // 768 x 768
    u16* Qb     = (u16*)alloc((size_t)M * NXC * 2);
    u16* Kb     = (u16*)alloc((size_t)M * NXC * 2);
    u16* Vb     = (u16*)alloc((size_t)M * NXC * 2);         // natural
    u16* Vtg    = (u16*)alloc((size_t)M * NXC * 2);         // per-head [d][s]
    u16* Ab     = (u16*)alloc((size_t)M * NXC * 2);
    u16* Opart  = (u16*)alloc((size_t)BSZ * NHEAD * NCHUNK * 128 * 64 * 2);
    float* Lpart = (float*)alloc((size_t)BSZ * NHEAD * NCHUNK * 128 * 4);

    // prep
    {
        int n4 = M * NXC / 4;
        cast4_kernel<<<dim3((n4 + 255) / 256), dim3(256), 0, stream>>>(hs, HSbf, n4);
        transpose_cast_kernel<<<dim3(3 * NXC / 32, NXC / 32), dim3(32, 8), 0, stream>>>(w_attn, WaT, NXC, 3 * NXC);
        transpose_cast_kernel<<<dim3(NXC / 32, NXC / 32), dim3(32, 8), 0, stream>>>(w_proj, WpT, NXC, NXC);
    }
    // qkv gemm: M=4096, N=2304, K=768 -> bf16 Q/K/V natural (K pre-scaled)
    gemm_bt_kernel<0><<<dim3(3 * NXC / 64, M / 128), dim3(256), 0, stream>>>(
        HSbf, WaT, b_attn, Qb, Kb, Vb, nullptr, M, 3 * NXC, NXC);
    // per-head V transpose
    vt_kernel<<<dim3(SEQ / 64, BSZ * NHEAD), dim3(256), 0, stream>>>(Vb, Vtg);
    // attention: split-K partials, then combine
    attn_mfma_kernel<<<dim3(NCHUNK, BSZ * NHEAD), dim3(512), 0, stream>>>(
        Qb, Kb, Vtg, amask, Opart, Lpart);
    attn_combine_kernel<<<dim3(SEQ / 32, BSZ * NHEAD), dim3(256), 0, stream>>>(
        Opart, Lpart, Ab);
    // proj gemm: M=4096, N=768, K=768 -> d_out fp32
    gemm_bt_kernel<1><<<dim3(NXC / 64, M / 128), dim3(256), 0, stream>>>(
        Ab, WpT, b_proj, nullptr, nullptr, nullptr, out, M, NXC, NXC);
}

// Round 13
// 170.947 us; speedup vs baseline: 1.6628x; 1.0169x over previous
//
#include <hip/hip_runtime.h>
#include <hip/hip_bf16.h>

typedef unsigned short u16;
typedef short bf16x8 __attribute__((ext_vector_type(8)));
typedef float f32x4 __attribute__((ext_vector_type(4)));

#define NXC 768
#define NHEAD 12
#define SEQ 2048
#define BSZ 2
#define HD 64
#define NCHUNK 72   // sum over 16 q-tiles of ceil(128*(bx+1)/256)
#define LOG2E 1.4426950408889634f

__device__ inline u16 f2bf(float f) {
    unsigned int u = __float_as_uint(f);
    unsigned int r = u + 0x7fffu + ((u >> 16) & 1u);
    return (u16)(r >> 16);
}
__device__ inline unsigned pk2(float lo, float hi) {
    return (unsigned)f2bf(lo) | ((unsigned)f2bf(hi) << 16);
}
__device__ inline float ex2(float x) { return __builtin_amdgcn_exp2f(x); }

// ---------------- prep kernels ----------------
__global__ void cast4_kernel(const float* __restrict__ in, u16* __restrict__ out, int n4) {
    int i = blockIdx.x * 256 + threadIdx.x;
    if (i >= n4) return;
    float4 v = ((const float4*)in)[i];
    ushort4 o;
    o.x = f2bf(v.x); o.y = f2bf(v.y); o.z = f2bf(v.z); o.w = f2bf(v.w);
    ((ushort4*)out)[i] = o;
}

// out[C][R] = in[R][C], fp32 -> bf16
__global__ void transpose_cast_kernel(const float* __restrict__ in, u16* __restrict__ out,
                                      int R, int C) {
    __shared__ float tile[32][33];
    int cb = blockIdx.x * 32, rb = blockIdx.y * 32;
    int tx = threadIdx.x, ty = threadIdx.y;   // block (32,8)
    #pragma unroll
    for (int i = 0; i < 32; i += 8)
        tile[ty + i][tx] = in[(size_t)(rb + ty + i) * C + cb + tx];
    __syncthreads();
    #pragma unroll
    for (int i = 0; i < 32; i += 8)
        out[(size_t)(cb + ty + i) * R + rb + tx] = f2bf(tile[tx][ty + i]);
}

// per-head transpose: Vb head-chunk [ss][dd] -> Vtg [dd][ss] (both bf16)
__global__ __launch_bounds__(256) void vt_kernel(const u16* __restrict__ Vb,
                                                 u16* __restrict__ Vtg) {
    __shared__ u16 tile[64][68];
    int y = blockIdx.y;                        // b*NHEAD+h
    size_t base = (size_t)y * (SEQ * HD);
    int ss0 = blockIdx.x * 64;
    int t = threadIdx.x;
    #pragma unroll
    for (int c = t; c < 512; c += 256) {
        int r = c >> 3, col = (c & 7) * 8;
        *(uint4*)&tile[r][col] = *(const uint4*)&Vb[base + (size_t)(ss0 + r) * HD + col];
    }
    __syncthreads();
    #pragma unroll
    for (int c = t; c < 512; c += 256) {
        int dd = c >> 3, s8 = (c & 7) * 8;
        ushort4 a, bq;
        a.x = tile[s8 + 0][dd]; a.y = tile[s8 + 1][dd];
        a.z = tile[s8 + 2][dd]; a.w = tile[s8 + 3][dd];
        bq.x = tile[s8 + 4][dd]; bq.y = tile[s8 + 5][dd];
        bq.z = tile[s8 + 6][dd]; bq.w = tile[s8 + 7][dd];
        u16* dst = &Vtg[base + (size_t)dd * SEQ + ss0 + s8];
        *(ushort4*)dst = a;
        *(ushort4*)(dst + 4) = bq;
    }
}

// ---------------- GEMM: C[M][N] = A[M][K] * BT[N][K]^T + bias ----------------
// 128M x 64N tile, BK=32, 256 threads (4 waves x 32M x 64N), register-prefetch
// pipeline (3x uint4 — known spill-free; BK=64/6x uint4 spilled).
// EPI 0: bf16 Q, K (pre-scaled 0.125*log2e), V natural. EPI 1: fp32 out[M][N].
template <int EPI>
__global__ __launch_bounds__(256) void gemm_bt_kernel(
    const u16* __restrict__ A, const u16* __restrict__ BT,
    const float* __restrict__ bias,
    u16* __restrict__ outQ, u16* __restrict__ outK, u16* __restrict__ outV,
    float* __restrict__ outF,
    int M, int N, int K) {
    __shared__ u16 As[128 * 32];
    __shared__ u16 Bs[64 * 32];
    int tileM = blockIdx.y * 128, tileN = blockIdx.x * 64;
    int t = threadIdx.x;
    int lane = t & 63, wave = t >> 6;
    int wm = wave * 32;
    int quad = lane >> 4, l16 = lane & 15;
    f32x4 acc[2][4] = {};

    int r0 = t >> 2, c0 = (t & 3) * 8;
    const u16* Ag0 = A + (size_t)(tileM + r0) * K + c0;
    const u16* Ag1 = Ag0 + (size_t)64 * K;
    const u16* Bg0 = BT + (size_t)(tileN + r0) * K + c0;   // r0 in 0..63
    u16* AsW0 = &As[r0 * 32 + c0];
    u16* AsW1 = &As[(r0 + 64) * 32 + c0];
    u16* BsW0 = &Bs[(r0 & 63) * 32 + c0];

    uint4 ra0 = *(const uint4*)(Ag0);
    uint4 ra1 = *(const uint4*)(Ag1);
    uint4 rb0 = *(const uint4*)(Bg0);

    for (int k0 = 0; k0 < K; k0 += 32) {
        __syncthreads();
        *(uint4*)AsW0 = ra0;
        *(uint4*)AsW1 = ra1;
        *(uint4*)BsW0 = rb0;
        __syncthreads();
        if (k0 + 32 < K) {
            ra0 = *(const uint4*)(Ag0 + k0 + 32);
            ra1 = *(const uint4*)(Ag1 + k0 + 32);
            rb0 = *(const uint4*)(Bg0 + k0 + 32);
        }
        bf16x8 af[2], bfr[4];
        #pragma unroll
        for (int i = 0; i < 2; ++i)
            af[i] = *(const bf16x8*)&As[(wm + i * 16 + l16) * 32 + quad * 8];
        #pragma unroll
        for (int j = 0; j < 4; ++j)
            bfr[j] = *(const bf16x8*)&Bs[(j * 16 + l16) * 32 + quad * 8];
        #pragma unroll
        for (int i = 0; i < 2; ++i)
            #pragma unroll
            for (int j = 0; j < 4; ++j)
                acc[i][j] = __builtin_amdgcn_mfma_f32_16x16x32_bf16(af[i], bfr[j], acc[i][j], 0, 0, 0);
    }

    #pragma unroll
    for (int i = 0; i < 2; ++i) {
        #pragma unroll
        for (int j = 0; j < 4; ++j) {
            int n = tileN + j * 16 + l16;
            float bv = bias[n];
            #pragma unroll
            for (int r = 0; r < 4; ++r) {
                int m = tileM + wm + i * 16 + quad * 4 + r;
                float v = acc[i][j][r] + bv;
                if (EPI == 0) {
                    if (n < 768) {
                        outQ[(size_t)m * 768 + n] = f2bf(v);
                    } else if (n < 1536) {
                        outK[(size_t)m * 768 + (n - 768)] = f2bf(v * (0.125f * LOG2E));
                    } else {
                        outV[(size_t)m * 768 + (n - 1536)] = f2bf(v);
                    }
                } else {
                    outF[(size_t)m * N + n] = v;
                }
            }
        }
    }
}

// ---------------- MFMA flash attention, split-K (256-key chunks) ----------------
// grid (NCHUNK, BSZ*NHEAD), block 512: 8 waves x 16 q-rows. Fixed-max softmax.
// Scores in base-2 domain (K pre-scaled 0.125*log2e, amask scaled log2e).
__global__ __launch_bounds__(512) void attn_mfma_kernel(
    const u16* __restrict__ Q, const u16* __restrict__ Kg,
    const u16* __restrict__ Vtg, const float* __restrict__ amask,
    u16* __restrict__ Opart, float* __restrict__ Lpart) {
    __shared__ u16 Ks[64][72];
    __shared__ u16 Vt[64][72];          // V^T tile: [d][key]
    __shared__ u16 Ps[8][16][72];       // per-wave P [q][key]
    __shared__ float Ams[64];

    int bh = blockIdx.y;
    int b = bh / NHEAD, h = bh % NHEAD;
    int p = NCHUNK - 1 - (int)blockIdx.x;   // heavy chunks dispatch first
    int bx = 15, c = 0, a = 0;
    #pragma unroll
    for (int i = 0; i < 16; ++i) {
        int n = (i + 2) >> 1;               // chunks for q-tile i (256-key chunks)
        if (p < a + n) { bx = i; c = p - a; break; }
        a += n;
    }
    int kbase = c * 256;
    int nt = 2 * (bx + 1) - 4 * c;          // 64-key tiles in this chunk
    if (nt > 4) nt = 4;

    int t = threadIdx.x;
    int w = t >> 6, lane = t & 63;
    int quad = lane >> 4, l16 = lane & 15;
    size_t headbase = (size_t)b * (SEQ * NXC) + (size_t)h * (SEQ * HD);
    size_t headbaseT = (size_t)(b * NHEAD + h) * (SEQ * HD);

    int r0 = bx * 128;
    int qw0 = r0 + w * 16;                  // wave owns 16 q-rows
    int qrow = qw0 + l16;
    bf16x8 qf[2];
    #pragma unroll
    for (int s = 0; s < 2; ++s)
        qf[s] = *(const bf16x8*)&Q[headbase + (size_t)(qw0 + l16) * HD + s * 32 + quad * 8];

    float l_part = 0.f;                     // per-lane partial of l
    f32x4 o[4] = {};

    // register prefetch of tile 0 (512 threads cover 64x64 K and V^T tiles)
    int pr_row = t >> 3, pr_col = (t & 7) * 8;
    uint4 kr, vr; float amr;
    {
        int k0 = kbase;
        kr = *(const uint4*)&Kg[headbase + (size_t)(k0 + pr_row) * HD + pr_col];
        vr = *(const uint4*)&Vtg[headbaseT + (size_t)pr_row * SEQ + k0 + pr_col];
        if (t < 64) amr = amask[(size_t)b * SEQ + k0 + t];
    }

    for (int kt = 0; kt < nt; ++kt) {
        int k0 = kbase + kt * 64;
        __syncthreads();
        *(uint4*)&Ks[pr_row][pr_col] = kr;
        *(uint4*)&Vt[pr_row][pr_col] = vr;
        if (t < 64) Ams[t] = amr * LOG2E;
        __syncthreads();
        if (kt + 1 < nt) {
            int kn = k0 + 64;
            kr = *(const uint4*)&Kg[headbase + (size_t)(kn + pr_row) * HD + pr_col];
            vr = *(const uint4*)&Vtg[headbaseT + (size_t)pr_row * SEQ + kn + pr_col];
            if (t < 64) amr = amask[(size_t)b * SEQ + kn + t];
        }

        if (k0 > qw0 + 15) continue;        // tile fully past-causal for this wave

        bf16x8 kf[2][4];
        #pragma unroll
        for (int s = 0; s < 2; ++s)
            #pragma unroll
            for (int j = 0; j < 4; ++j)
                kf[s][j] = *(const bf16x8*)&Ks[j * 16 + l16][s * 32 + quad * 8];
        float amv[4][4];
        #pragma unroll
        for (int j = 0; j < 4; ++j)
            #pragma unroll
            for (int r = 0; r < 4; ++r)
                amv[j][r] = Ams[j * 16 + quad * 4 + r];

        // S^T = K * Q^T : lane owns q-row = l16
        f32x4 sacc[4] = {};
        #pragma unroll
        for (int s = 0; s < 2; ++s)
            #pragma unroll
            for (int j = 0; j < 4; ++j)
                sacc[j] = __builtin_amdgcn_mfma_f32_16x16x32_bf16(kf[s][j], qf[s], sacc[j], 0, 0, 0);

        bool diag = (k0 + 63 > qw0);
        #pragma unroll
        for (int j = 0; j < 4; ++j) {
            float pv[4];
            #pragma unroll
            for (int r = 0; r < 4; ++r) {
                float pp = ex2(sacc[j][r] + amv[j][r]);
                if (diag && (k0 + j * 16 + quad * 4 + r > qrow)) pp = 0.f;
                pv[r] = pp;
            }
            l_part += (pv[0] + pv[1]) + (pv[2] + pv[3]);
            unsigned pk01 = ((__float_as_uint(pv[0]) + 0x8000u) >> 16) |
                            ((__float_as_uint(pv[1]) + 0x8000u) & 0xffff0000u);
            unsigned pk23 = ((__float_as_uint(pv[2]) + 0x8000u) >> 16) |
                            ((__float_as_uint(pv[3]) + 0x8000u) & 0xffff0000u);
            *(uint2*)&Ps[w][l16][j * 16 + quad * 4] = make_uint2(pk01, pk23);
        }

        // PV: O[q][d] += P[q][k] * Vt[d][k]^T   (no rescale — fixed m)
        #pragma unroll
        for (int s = 0; s < 2; ++s) {
            bf16x8 pf = *(const bf16x8*)&Ps[w][l16][s * 32 + quad * 8];
            #pragma unroll
            for (int dc = 0; dc < 4; ++dc) {
                bf16x8 vf = *(const bf16x8*)&Vt[dc * 16 + l16][s * 32 + quad * 8];
                o[dc] = __builtin_amdgcn_mfma_f32_16x16x32_bf16(pf, vf, o[dc], 0, 0, 0);
            }
        }
    }

    // epilogue: reduce l across quads once, write unnormalized partials
    float l = l_part + __shfl_xor(l_part, 16);
    l += __shfl_xor(l, 32);
    u16* Ob = Opart + ((size_t)bh * NCHUNK + p) * (128 * 64);
    float* Lb = Lpart + ((size_t)bh * NCHUNK + p) * 128;
    #pragma unroll
    for (int dc = 0; dc < 4; ++dc)
        #pragma unroll
        for (int r = 0; r < 4; ++r) {
            int rl = w * 16 + quad * 4 + r;
            Ob[rl * 64 + dc * 16 + l16] = f2bf(o[dc][r]);
        }
    if (quad == 0) Lb[w * 16 + l16] = l;
}

// ---------------- combine partials -> bf16 A (vectorized, high-parallelism) ----
// grid (SEQ/32, BSZ*NHEAD), block 256: each block does 32 rows x 64 dims.
__global__ __launch_bounds__(256) void attn_combine_kernel(
    const u16* __restrict__ Opart, const float* __restrict__ Lpart,
    u16* __restrict__ Aout) {
    __shared__ float winv[32];
    int bh = blockIdx.y;
    int b = bh / NHEAD, h = bh % NHEAD;
    int row0 = blockIdx.x * 32;             // global q-row base
    int bx = row0 >> 7;                     // 128-row q-tile
    int nch = (bx + 2) >> 1;                // chunks for this tile (256-key)
    int m = bx >> 1;
    int p0 = (bx & 1) ? (m + 1) * (m + 1) : m * (m + 1);
    int rbase = row0 & 127;                 // row offset within the 128-tile
    int t = threadIdx.x;

    if (t < 32) {
        float L = 0.f;
        for (int c = 0; c < nch; ++c)
            L += Lpart[((size_t)bh * NCHUNK + p0 + c) * 128 + rbase + t];
        winv[t] = 1.0f / L;
    }
    __syncthreads();

    int row = t >> 3;                       // 0..31
    int d0 = (t & 7) * 8;
    int rl = rbase + row;
    float acc[8] = {};
    for (int c = 0; c < nch; ++c) {
        uint4 u = *(const uint4*)&Opart[(((size_t)bh * NCHUNK + p0 + c) * 128 + rl) * 64 + d0];
        acc[0] += __uint_as_float(u.x << 16);
        acc[1] += __uint_as_float(u.x & 0xffff0000u);
        acc[2] += __uint_as_float(u.y << 16);
        acc[3] += __uint_as_float(u.y & 0xffff0000u);
        acc[4] += __uint_as_float(u.z << 16);
        acc[5] += __uint_as_float(u.z & 0xffff0000u);
        acc[6] += __uint_as_float(u.w << 16);
        acc[7] += __uint_as_float(u.w & 0xffff0000u);
    }
    float s = winv[row];
    uint4 o;
    o.x = pk2(acc[0] * s, acc[1] * s);
    o.y = pk2(acc[2] * s, acc[3] * s);
    o.z = pk2(acc[4] * s, acc[5] * s);
    o.w = pk2(acc[6] * s, acc[7] * s);
    *(uint4*)&Aout[((size_t)b * SEQ + row0 + row) * NXC + h * HD + d0] = o;
}

// ---------------- launcher ----------------
extern "C" void kernel_launch(void* const* d_in, const int* in_sizes, int n_in,
                              void* d_out, int out_size, void* d_ws, size_t ws_size,
                              hipStream_t stream) {
    const float* hs     = (const float*)d_in[0];
    const float* amask  = (const float*)d_in[1];
    const float* w_attn = (const float*)d_in[2];
    const float* b_attn = (const float*)d_in[3];
    const float* w_proj = (const float*)d_in[4];
    const float* b_proj = (const float*)d_in[5];
    float* out = (float*)d_out;

    const int M = BSZ * SEQ;            // 4096
    char* ws = (char*)d_ws;
    auto alloc = [&](size_t bytes) {
        char* p = ws;
        ws += (bytes + 255) & ~(size_t)255;
        return p;
    };
    u16* HSbf   = (u16*)alloc((size_t)M * NXC * 2);
    u16* WaT    = (u16*)alloc((size_t)3 * NXC * NXC * 2);   // 2304 x 768
    u16* WpT    = (u16*)alloc((size_t)NXC * NXC * 2);       // 768 x 768
    u16* Qb     = (u16*)alloc((size_t)M * NXC * 2);
    u16* Kb     = (u16*)alloc((size_t)M * NXC * 2);
    u16* Vb     = (u16*)alloc((size_t)M * NXC * 2);         // natural
    u16* Vtg    = (u16*)alloc((size_t)M * NXC * 2);         // per-head [d][s]
    u16* Ab     = (u16*)alloc((size_t)M * NXC * 2);
    u16* Opart  = (u16*)alloc((size_t)BSZ * NHEAD * NCHUNK * 128 * 64 * 2);
    float* Lpart = (float*)alloc((size_t)BSZ * NHEAD * NCHUNK * 128 * 4);

    // prep
    {
        int n4 = M * NXC / 4;
        cast4_kernel<<<dim3((n4 + 255) / 256), dim3(256), 0, stream>>>(hs, HSbf, n4);
        transpose_cast_kernel<<<dim3(3 * NXC / 32, NXC / 32), dim3(32, 8), 0, stream>>>(w_attn, WaT, NXC, 3 * NXC);
        transpose_cast_kernel<<<dim3(NXC / 32, NXC / 32), dim3(32, 8), 0, stream>>>(w_proj, WpT, NXC, NXC);
    }
    // qkv gemm: M=4096, N=2304, K=768 -> bf16 Q/K/V natural (K pre-scaled)
    gemm_bt_kernel<0><<<dim3(3 * NXC / 64, M / 128), dim3(256), 0, stream>>>(
        HSbf, WaT, b_attn, Qb, Kb, Vb, nullptr, M, 3 * NXC, NXC);
    // per-head V transpose
    vt_kernel<<<dim3(SEQ / 64, BSZ * NHEAD), dim3(256), 0, stream>>>(Vb, Vtg);
    // attention: split-K partials (256-key chunks), then combine
    attn_mfma_kernel<<<dim3(NCHUNK, BSZ * NHEAD), dim3(512), 0, stream>>>(
        Qb, Kb, Vtg, amask, Opart, Lpart);
    attn_combine_kernel<<<dim3(SEQ / 32, BSZ * NHEAD), dim3(256), 0, stream>>>(
        Opart, Lpart, Ab);
    // proj gemm: M=4096, N=768, K=768 -> d_out fp32
    gemm_bt_kernel<1><<<dim3(NXC / 64, M / 128), dim3(256), 0, stream>>>(
        Ab, WpT, b_proj, nullptr, nullptr, nullptr, out, M, NXC, NXC);
}